// Round 1
// baseline (4621.471 us; speedup 1.0000x reference)
//
#include <hip/hip_runtime.h>

#define NLAYER 6
#define NB     128     // batch
#define NT     512     // seq len
#define DIN    128     // layer-0 input size
#define NH     256     // hidden
#define NBLK   192     // 6 layers x 16 slices x 2 batch-groups, all co-resident
// Tagged ring: each h value is one 4B word = (bf16<<16)|step_tag.
// Slot = [128 batch rows][256 words] = [128][128 u64] = 16384 u64 = 128KB.
#define SLOT_U64 (NB*NH/2)

typedef __attribute__((ext_vector_type(8))) short short8;
typedef __attribute__((ext_vector_type(4))) float f32x4;
typedef unsigned long long u64;

__device__ __forceinline__ unsigned f2bf2(float lo, float hi){
  unsigned a = __float_as_uint(lo), b = __float_as_uint(hi);
  a = (a + 0x7fffu + ((a>>16)&1u)) >> 16;   // RNE bf16
  b = (b + 0x7fffu + ((b>>16)&1u)) >> 16;
  return a | (b<<16);
}
__device__ __forceinline__ u64 f2bf4(float a, float b, float c, float d){
  return (u64)f2bf2(a,b) | ((u64)f2bf2(c,d) << 32);
}
__device__ __forceinline__ short8 pack16(u64 lo, u64 hi){
  union { u64 u[2]; short8 v; } w; w.u[0]=lo; w.u[1]=hi; return w.v;
}
// 8 consecutive fp32 -> one MFMA bf16 fragment (4 VGPRs)
__device__ __forceinline__ short8 ld8f_frag(const float* p){
  f32x4 a = *(const f32x4*)p;
  f32x4 b = *(const f32x4*)(p+4);
  return pack16(f2bf4(a[0],a[1],a[2],a[3]), f2bf4(b[0],b[1],b[2],b[3]));
}

__device__ __forceinline__ float sigmf(float v){ return 1.0f/(1.0f + __expf(-v)); }
__device__ __forceinline__ float tanhfast(float v){
  v = fminf(fmaxf(v, -15.0f), 15.0f);
  float e = __expf(2.0f*v);
  return (e - 1.0f)/(e + 1.0f);
}

// Relaxed agent-scope atomics (device-coherent at the fabric). With the
// self-validating tagged-word format the ONLY requirement is per-4B-word
// atomic visibility: every word carries its own step tag, so no store
// ordering, no vmcnt drain, no separate tag arrays are needed.
__device__ __forceinline__ int ld_flag(int* p){
  return __hip_atomic_load(p, __ATOMIC_RELAXED, __HIP_MEMORY_SCOPE_AGENT);
}
__device__ __forceinline__ void st_flag(int* p, int v){
  __hip_atomic_store(p, v, __ATOMIC_RELAXED, __HIP_MEMORY_SCOPE_AGENT);
}
__device__ __forceinline__ u64 ring_ld(const u64* p){
  return __hip_atomic_load(p, __ATOMIC_RELAXED, __HIP_MEMORY_SCOPE_AGENT);
}
__device__ __forceinline__ void ring_st(u64* p, u64 v){
  __hip_atomic_store(p, v, __ATOMIC_RELAXED, __HIP_MEMORY_SCOPE_AGENT);
}

// pack two h values + step tag into one self-validating u64 (two 4B words)
__device__ __forceinline__ u64 tagpack2(float a, float b, unsigned tag){
  unsigned ua = __float_as_uint(a), ub = __float_as_uint(b);
  ua = (ua + 0x7fffu + ((ua>>16)&1u)) & 0xffff0000u;   // RNE bf16 in hi16
  ub = (ub + 0x7fffu + ((ub>>16)&1u)) & 0xffff0000u;
  return (u64)(ua|tag) | ((u64)(ub|tag) << 32);
}
// 4 tagged u64 (8 words) -> one MFMA bf16 fragment: strip tags via v_perm
__device__ __forceinline__ short8 untag4(const u64 w[4]){
  union { unsigned u[4]; short8 v; } o;
  #pragma unroll
  for (int j = 0; j < 4; ++j)
    o.u[j] = __builtin_amdgcn_perm((unsigned)(w[j]>>32), (unsigned)w[j], 0x07060302u);
  return o.v;
}
__device__ __forceinline__ unsigned tagdiff(u64 w, unsigned tag){
  return ((unsigned)w ^ tag) | ((unsigned)(w>>32) ^ tag);
}

// Poll a tagged fragment set (NK k-steps, 4 u64 each) until every 4B word
// carries `tag`. On exit the accepted data is already in registers.
template<int NK>
__device__ __forceinline__ void poll_tag(const u64* __restrict__ base, unsigned tag, short8* B){
  u64 w[NK][4];
  int guard = 0;
  for (;;){
    #pragma unroll
    for (int k = 0; k < NK; ++k){
      #pragma unroll
      for (int j = 0; j < 4; ++j) w[k][j] = ring_ld(base + k*16 + j);
    }
    unsigned bad = 0;
    #pragma unroll
    for (int k = 0; k < NK; ++k)
      #pragma unroll
      for (int j = 0; j < 4; ++j) bad |= tagdiff(w[k][j], tag);
    if (__ballot((bad & 0xffffu) == 0u) == ~0ull) break;
    __builtin_amdgcn_s_sleep(1);
    if (++guard > (1<<22)) break;   // failsafe only
  }
  #pragma unroll
  for (int k = 0; k < NK; ++k) B[k] = untag4(w[k]);
}

// Combined x+h tagged poll: one loop, both detect latencies overlap; the
// side that validated first is not re-loaded on retries.
template<int NKX2, int NKH2>
__device__ __forceinline__ void poll_xh(const u64* __restrict__ xb, unsigned xtag,
                                        const u64* __restrict__ hb, unsigned htag,
                                        short8* Bx, short8* Bh){
  u64 wx[NKX2][4], wh[NKH2][4];
  bool okx = false, okh = false;
  int guard = 0;
  for (;;){
    if (!okx){
      #pragma unroll
      for (int k = 0; k < NKX2; ++k){
        #pragma unroll
        for (int j = 0; j < 4; ++j) wx[k][j] = ring_ld(xb + k*16 + j);
      }
    }
    if (!okh){
      #pragma unroll
      for (int k = 0; k < NKH2; ++k){
        #pragma unroll
        for (int j = 0; j < 4; ++j) wh[k][j] = ring_ld(hb + k*16 + j);
      }
    }
    if (!okx){
      unsigned bad = 0;
      #pragma unroll
      for (int k = 0; k < NKX2; ++k)
        #pragma unroll
        for (int j = 0; j < 4; ++j) bad |= tagdiff(wx[k][j], xtag);
      okx = (__ballot((bad & 0xffffu) == 0u) == ~0ull);
    }
    if (!okh){
      unsigned bad = 0;
      #pragma unroll
      for (int k = 0; k < NKH2; ++k)
        #pragma unroll
        for (int j = 0; j < 4; ++j) bad |= tagdiff(wh[k][j], htag);
      okh = (__ballot((bad & 0xffffu) == 0u) == ~0ull);
    }
    if (okx && okh) break;
    __builtin_amdgcn_s_sleep(1);
    if (++guard > (1<<22)) break;   // failsafe only
  }
  #pragma unroll
  for (int k = 0; k < NKX2; ++k) Bx[k] = untag4(wx[k]);
  #pragma unroll
  for (int k = 0; k < NKH2; ++k) Bh[k] = untag4(wh[k]);
}

// Wave-dataflow LSTM, tagged-ring edition. Each wave owns a 16h x 16b tile;
// A stationary in regs; h published as self-tagged words (no drains, no tag
// arrays). Cross-layer wrap protected by amortized acks (every 8 steps).
template<int NKX, int KIT>
__device__ __forceinline__ void lstm_run(
    const float* __restrict__ x,  const float* __restrict__ h0,
    const float* __restrict__ c0, const float* __restrict__ wx,
    const float* __restrict__ wh, const float* __restrict__ bi,
    const float* __restrict__ bh, float* __restrict__ out,
    int* __restrict__ acks, u64* __restrict__ ring,
    int Wv, int l, int s, int g, int wv, int lane)
{
  constexpr int NKH = KIT - NKX;    // h-part k-iterations (8)
  constexpr int KX  = NKX*32;       // input width (128 or 256)
  const int l15  = lane & 15;
  const int quad = lane >> 4;
  const int bloc = g*64 + wv*16 + l15;   // this lane's batch row
  const int jcol = s*16 + quad*4;        // this lane's first hidden col
  const int Wm   = Wv - 1;

  // ---- A fragments: stationary (4 gates x KIT kts x 4 VGPR) ----
  short8 A[4][KIT];
  #pragma unroll
  for (int q = 0; q < 4; ++q){
    const float* wrow_x = wx + (size_t)(q*NH + s*16 + l15)*KX;
    const float* wrow_h = wh + (size_t)(q*NH + s*16 + l15)*NH;
    #pragma unroll
    for (int kt = 0; kt < KIT; ++kt){
      int k0 = kt*32 + quad*8;
      A[q][kt] = (k0 < KX) ? ld8f_frag(wrow_x + k0)
                           : ld8f_frag(wrow_h + (k0 - KX));
    }
  }

  f32x4 bsv[4];
  #pragma unroll
  for (int q = 0; q < 4; ++q){
    f32x4 a = *(const f32x4*)(bi + q*NH + jcol);
    f32x4 b = *(const f32x4*)(bh + q*NH + jcol);
    bsv[q] = a + b;
  }
  float cc[4];
  {
    f32x4 cv = *(const f32x4*)(c0 + ((size_t)l*NB + bloc)*NH + jcol);
    cc[0]=cv[0]; cc[1]=cv[1]; cc[2]=cv[2]; cc[3]=cv[3];
  }

  // acks[(l*2+g)*4+wv][s]: how far wave (l,s,wv,g) has consumed prev-layer ring
  int* ackNext = acks + (((l+1)*2 + g)*4 + wv)*16;   // consumers of OUR ring (l<5)
  int* ackSelf = acks + ((l*2 + g)*4 + wv)*16 + s;   // our own consumption mark (l>0)
  const u64* ringPrev = ring + (size_t)(l > 0 ? l-1 : 0)*Wv*SLOT_U64;
  u64*       ringOwn  = ring + (size_t)l*Wv*SLOT_U64;
  const bool lastL = (l == NLAYER-1);
  const bool wrap  = (Wv < NT);
  int ackmin = 0;

  for (int t = 0; t < NT; ++t){
    const int slot  = t & Wm;
    const int pslot = (t-1) & Wm;

    // WAR guard before overwriting slot t: next layer must have consumed
    // slot t-Wv. Amortized: consumer acks jump by 8, so this polls ~1/8 steps.
    if (wrap && !lastL && t >= Wv){
      const int need = t - Wv + 1;
      if (ackmin < need){
        int v = 0, guard = 0;
        for (;;){
          v = (lane < 16) ? ld_flag(ackNext + lane) : 0x7fffffff;
          if (__ballot(v >= need) == ~0ull) break;
          __builtin_amdgcn_s_sleep(1);
          if (++guard > (1<<22)) break;
        }
        int m = v;
        #pragma unroll
        for (int o = 8; o; o >>= 1) m = min(m, __shfl_xor(m, o));
        ackmin = __shfl(m, 0);   // cached watermark
      }
    }

    short8 Bx[NKX], Bh[NKH];
    if constexpr (NKX == 4){
      // layer 0: x is a plain L2-cached load, issued before the h poll
      const float* px = x + ((size_t)bloc*NT + t)*DIN + quad*8;
      #pragma unroll
      for (int k = 0; k < NKX; ++k) Bx[k] = ld8f_frag(px + k*32);
      if (t == 0){
        const float* ph = h0 + ((size_t)l*NB + bloc)*NH + quad*8;
        #pragma unroll
        for (int k = 0; k < NKH; ++k) Bh[k] = ld8f_frag(ph + k*32);
      } else {
        const u64* hb = ringOwn + (size_t)pslot*SLOT_U64 + bloc*128 + quad*4;
        poll_tag<NKH>(hb, (unsigned)t, Bh);
      }
    } else {
      const u64* xb = ringPrev + (size_t)slot*SLOT_U64 + bloc*128 + quad*4;
      if (t == 0){
        poll_tag<NKX>(xb, 1u, Bx);
        const float* ph = h0 + ((size_t)l*NB + bloc)*NH + quad*8;
        #pragma unroll
        for (int k = 0; k < NKH; ++k) Bh[k] = ld8f_frag(ph + k*32);
      } else {
        const u64* hb = ringOwn + (size_t)pslot*SLOT_U64 + bloc*128 + quad*4;
        poll_xh<NKX, NKH>(xb, (unsigned)(t+1), hb, (unsigned)t, Bx, Bh);
      }
      // ack prev-layer consumption every 8 steps (x loads proven complete:
      // their values were branched on in the poll). No drain needed.
      if (wrap && ((t & 7) == 7)){
        asm volatile("" ::: "memory");
        if (lane == 0) st_flag(ackSelf, t+1);
      }
    }

    // ---- MFMAs: x-part first, then h-part ----
    f32x4 a0 = {0,0,0,0}, a1 = {0,0,0,0}, a2 = {0,0,0,0}, a3 = {0,0,0,0};
    #pragma unroll
    for (int k = 0; k < NKX; ++k){
      a0 = __builtin_amdgcn_mfma_f32_16x16x32_bf16(A[0][k], Bx[k], a0, 0, 0, 0);
      a1 = __builtin_amdgcn_mfma_f32_16x16x32_bf16(A[1][k], Bx[k], a1, 0, 0, 0);
      a2 = __builtin_amdgcn_mfma_f32_16x16x32_bf16(A[2][k], Bx[k], a2, 0, 0, 0);
      a3 = __builtin_amdgcn_mfma_f32_16x16x32_bf16(A[3][k], Bx[k], a3, 0, 0, 0);
    }
    #pragma unroll
    for (int k = 0; k < NKH; ++k){
      a0 = __builtin_amdgcn_mfma_f32_16x16x32_bf16(A[0][NKX+k], Bh[k], a0, 0, 0, 0);
      a1 = __builtin_amdgcn_mfma_f32_16x16x32_bf16(A[1][NKX+k], Bh[k], a1, 0, 0, 0);
      a2 = __builtin_amdgcn_mfma_f32_16x16x32_bf16(A[2][NKX+k], Bh[k], a2, 0, 0, 0);
      a3 = __builtin_amdgcn_mfma_f32_16x16x32_bf16(A[3][NKX+k], Bh[k], a3, 0, 0, 0);
    }

    // ---- fused gate nonlinearities + state update ----
    float hv[4];
    #pragma unroll
    for (int r = 0; r < 4; ++r){
      float ig = sigmf(a0[r] + bsv[0][r]);
      float fg = sigmf(a1[r] + bsv[1][r]);
      float gv = tanhfast(a2[r] + bsv[2][r]);
      float og = sigmf(a3[r] + bsv[3][r]);
      float cn = fg*cc[r] + ig*gv;
      cc[r] = cn;
      hv[r] = og * tanhfast(cn);
    }

    // ---- publish: two self-tagged 8B stores. No vmcnt drain, no tag store.
    u64* hp = ringOwn + (size_t)slot*SLOT_U64 + bloc*128 + s*8 + quad*2;
    const unsigned otag = (unsigned)(t+1);
    ring_st(hp,     tagpack2(hv[0], hv[1], otag));
    ring_st(hp + 1, tagpack2(hv[2], hv[3], otag));
    if (t == NT-1){
      f32x4 ov; ov[0]=hv[0]; ov[1]=hv[1]; ov[2]=hv[2]; ov[3]=hv[3];
      *(f32x4*)(out + ((size_t)l*NB + bloc)*NH + jcol) = ov;
    }
  }
}

__global__ __launch_bounds__(256, 1)
void lstm_pipe(const float* __restrict__ x,   const float* __restrict__ h0,
               const float* __restrict__ c0,  const float* __restrict__ wih0,
               const float* __restrict__ wih, const float* __restrict__ whh,
               const float* __restrict__ bih, const float* __restrict__ bhh,
               float* __restrict__ out, int* __restrict__ acks,
               u64* __restrict__ ring, int Wv)
{
  const int tid  = threadIdx.x;
  const int bid  = blockIdx.x;
  const int l    = bid >> 5;          // 32 blocks per layer
  const int s    = (bid >> 1) & 15;
  const int g    = bid & 1;
  const int lane = tid & 63;
  const int wv   = tid >> 6;

  if (l == 0)
    lstm_run<4,12>(x, h0, c0, wih0, whh, bih, bhh,
                   out, acks, ring, Wv, 0, s, g, wv, lane);
  else
    lstm_run<8,16>(x, h0, c0,
                   wih + (size_t)(l-1)*(4*NH*NH),
                   whh + (size_t)l*(4*NH*NH),
                   bih + (size_t)l*(4*NH),
                   bhh + (size_t)l*(4*NH),
                   out, acks, ring, Wv, l, s, g, wv, lane);
}

extern "C" void kernel_launch(void* const* d_in, const int* in_sizes, int n_in,
                              void* d_out, int out_size, void* d_ws, size_t ws_size,
                              hipStream_t stream)
{
  (void)in_sizes; (void)n_in; (void)out_size;
  const float* x    = (const float*)d_in[0];
  const float* h0   = (const float*)d_in[1];
  const float* c0   = (const float*)d_in[2];
  const float* wih0 = (const float*)d_in[3];
  const float* wih  = (const float*)d_in[4];
  const float* whh  = (const float*)d_in[5];
  const float* bih  = (const float*)d_in[6];
  const float* bhh  = (const float*)d_in[7];

  // Ring depth 64 (48 MB): own-h needs only depth 2 (cohort is lockstep);
  // cross-layer wrap is covered by amortized acks. Shrink if ws is small.
  int Wv = 64;
  size_t ringB;
  for (;;){
    ringB = (size_t)NLAYER*Wv*SLOT_U64*8;
    if (4096 + ringB <= ws_size || Wv <= 4) break;
    Wv >>= 1;
  }

  int* acks = (int*)d_ws;                       // 768 ints, padded to 4KB
  u64* ring = (u64*)((char*)d_ws + 4096);

  // Ring MUST be cleared every launch: a replay would otherwise find the
  // previous run's tags (slot t tagged t+1) and accept stale data early.
  (void)hipMemsetAsync(d_ws, 0, 4096 + ringB, stream);
  hipLaunchKernelGGL(lstm_pipe, dim3(NBLK), dim3(256), 0, stream,
                     x, h0, c0, wih0, wih, whh, bih, bhh,
                     (float*)d_out, acks, ring, Wv);
}

// Round 2
// 2288.673 us; speedup vs baseline: 2.0193x; 2.0193x over previous
//
#include <hip/hip_runtime.h>

#define NLAYER 6
#define NB     128     // batch
#define NT     512     // seq len
#define DIN    128     // layer-0 input size
#define NH     256     // hidden
#define NBLK   192     // 6 layers x 8 batch-groups x 4 blocks
#define SLOT_U64 (NB*NH/4)   // ring slot = [128 bloc][64 u64 = 512B bf16] = 8192 u64

typedef __attribute__((ext_vector_type(8))) short short8;
typedef __attribute__((ext_vector_type(4))) float f32x4;
typedef unsigned long long u64;

__device__ __forceinline__ unsigned f2bf2(float lo, float hi){
  unsigned a = __float_as_uint(lo), b = __float_as_uint(hi);
  a = (a + 0x7fffu + ((a>>16)&1u)) >> 16;   // RNE bf16
  b = (b + 0x7fffu + ((b>>16)&1u)) >> 16;
  return a | (b<<16);
}
__device__ __forceinline__ u64 f2bf4(float a, float b, float c, float d){
  return (u64)f2bf2(a,b) | ((u64)f2bf2(c,d) << 32);
}
__device__ __forceinline__ short8 pack16(u64 lo, u64 hi){
  union { u64 u[2]; short8 v; } w; w.u[0]=lo; w.u[1]=hi; return w.v;
}
// 8 consecutive fp32 -> one MFMA bf16 fragment (4 VGPRs)
__device__ __forceinline__ short8 ld8f_frag(const float* p){
  f32x4 a = *(const f32x4*)p;
  f32x4 b = *(const f32x4*)(p+4);
  return pack16(f2bf4(a[0],a[1],a[2],a[3]), f2bf4(b[0],b[1],b[2],b[3]));
}

__device__ __forceinline__ float sigmf(float v){ return 1.0f/(1.0f + __expf(-v)); }
__device__ __forceinline__ float tanhfast(float v){
  v = fminf(fmaxf(v, -15.0f), 15.0f);
  float e = __expf(2.0f*v);
  return (e - 1.0f)/(e + 1.0f);
}

// Relaxed agent-scope atomics. Producer order: data stores -> s_waitcnt
// vmcnt(0) -> counter store. A consumer that observes the counter observes
// the data with later agent loads (round-0-proven protocol).
__device__ __forceinline__ int ld_flag(const int* p){
  return __hip_atomic_load(p, __ATOMIC_RELAXED, __HIP_MEMORY_SCOPE_AGENT);
}
__device__ __forceinline__ void st_flag(int* p, int v){
  __hip_atomic_store(p, v, __ATOMIC_RELAXED, __HIP_MEMORY_SCOPE_AGENT);
}
__device__ __forceinline__ u64 ring_ld(const u64* p){
  return __hip_atomic_load(p, __ATOMIC_RELAXED, __HIP_MEMORY_SCOPE_AGENT);
}
__device__ __forceinline__ void ring_st(u64* p, u64 v){
  __hip_atomic_store(p, v, __ATOMIC_RELAXED, __HIP_MEMORY_SCOPE_AGENT);
}

// Merged poll: lanes 0-15 poll the 16 h-counters (one 64B line, coalesced),
// lanes 16-31 poll the 16 x-counters of the previous layer. Counters are
// monotone per-producer step counts (no slots, no ABA).
__device__ __forceinline__ void poll2(const int* tH, int needH,
                                      const int* tX, int needX, int lane){
  const int* tp = nullptr; int need = 0;
  if (lane < 16)               { tp = tH + lane;        need = needH; }
  else if (tX && lane < 32)    { tp = tX + (lane - 16); need = needX; }
  int guard = 0;
  for (;;){
    int v = tp ? ld_flag(tp) : 0x7fffffff;
    if (__ballot(v >= need) == ~0ull) break;
    __builtin_amdgcn_s_sleep(1);
    if (++guard > (1<<22)) break;   // failsafe only
  }
  asm volatile("" ::: "memory");
}

// Stage one 16-bloc x 256-col bf16 plane (8KB) from the ring into LDS.
// Per wave: 4 rows; per lane: 32B contiguous -> fully coalesced agent loads.
// LDS row pitch 66 u64 (528B): +16B pad spreads frag ds_read_b128 banks.
__device__ __forceinline__ void stage_plane(const u64* __restrict__ src,
                                            u64* __restrict__ dst, int wv, int lane){
  const int r = lane >> 4, c = lane & 15;
  const u64* p = src + (size_t)(wv*4 + r)*64 + c*4;
  u64 v0 = ring_ld(p), v1 = ring_ld(p+1), v2 = ring_ld(p+2), v3 = ring_ld(p+3);
  u64* d = dst + (wv*4 + r)*66 + c*4;
  d[0] = v0; d[1] = v1; d[2] = v2; d[3] = v3;
}
// MFMA B-fragment straight out of the staged LDS plane (16B aligned).
__device__ __forceinline__ short8 lds_frag(const u64* __restrict__ buf, int row, int off){
  return *(const short8*)((const short*)buf + row*264 + off);
}

// Block = 4 slices x 16 batch rows. Wave wv owns slice s = b*4+wv (16 h-cols,
// 64 gate rows) for the block's 16 batch rows. h/x staged once per block into
// LDS (shared by all 4 waves); A stationary in regs.
template<int NKX>
__device__ __forceinline__ void lstm_run(
    const float* __restrict__ x,  const float* __restrict__ h0,
    const float* __restrict__ c0, const float* __restrict__ wx,
    const float* __restrict__ wh, const float* __restrict__ bi,
    const float* __restrict__ bh, float* __restrict__ out,
    int* __restrict__ tags, int* __restrict__ acks,
    u64* __restrict__ ring, u64 (*ldsb)[1056],
    int Wv, int l, int bg, int s, int wv, int lane)
{
  constexpr int KIT  = NKX + 8;      // total k-iterations (12 or 16)
  constexpr int KX   = NKX*32;       // input width (128 or 256)
  constexpr bool HASX = (NKX == 8);  // x comes from the prev-layer ring
  const int l15  = lane & 15;
  const int quad = lane >> 4;
  const int bloc = bg*16 + l15;      // this lane's batch row
  const int jcol = s*16 + quad*4;    // this lane's first hidden col
  const int Wm   = Wv - 1;

  // ---- A fragments: stationary (4 gates x KIT kts x 4 VGPR) ----
  short8 A[4][KIT];
  #pragma unroll
  for (int q = 0; q < 4; ++q){
    const float* wrow_x = wx + (size_t)(q*NH + s*16 + l15)*KX;
    const float* wrow_h = wh + (size_t)(q*NH + s*16 + l15)*NH;
    #pragma unroll
    for (int kt = 0; kt < KIT; ++kt){
      int k0 = kt*32 + quad*8;
      A[q][kt] = (k0 < KX) ? ld8f_frag(wrow_x + k0)
                           : ld8f_frag(wrow_h + (k0 - KX));
    }
  }

  f32x4 bsv[4];
  #pragma unroll
  for (int q = 0; q < 4; ++q){
    f32x4 a = *(const f32x4*)(bi + q*NH + jcol);
    f32x4 b = *(const f32x4*)(bh + q*NH + jcol);
    bsv[q] = a + b;
  }
  float cc[4];
  {
    f32x4 cv = *(const f32x4*)(c0 + ((size_t)l*NB + bloc)*NH + jcol);
    cc[0]=cv[0]; cc[1]=cv[1]; cc[2]=cv[2]; cc[3]=cv[3];
  }

  int* tagOwn   = tags + (l*8 + bg)*16;                       // our 16 producers
  const int* tagPrev = HASX ? tags + ((l-1)*8 + bg)*16 : nullptr;
  const int* ackOwn  = acks + (l*8 + bg)*16;                  // layer l+1's watermark
  int* ackPrevW = HASX ? acks + ((l-1)*8 + bg)*16 + s : nullptr;
  const u64* ringPrev = HASX ? ring + (size_t)(l-1)*Wv*SLOT_U64 : nullptr;
  u64*       ringOwn  = ring + (size_t)l*Wv*SLOT_U64;
  const bool lastL = (l == NLAYER-1);
  const bool wrap  = (Wv < NT);
  int ackmin = 0;

  for (int t = 0; t < NT; ++t){
    const int slot  = t & Wm;
    const int pslot = (t-1) & Wm;

    // WAR guard (ring wraps only): layer l+1 must have consumed slot t-Wv.
    // Consumers ack every 8 steps; cached watermark -> fabric poll ~1/8 steps.
    if (wrap && !lastL && t >= Wv){
      const int need = t - Wv + 1;
      if (ackmin < need){
        int v = 0, guard = 0;
        for (;;){
          v = (lane < 16) ? ld_flag(ackOwn + lane) : 0x7fffffff;
          if (__ballot(v >= need) == ~0ull) break;
          __builtin_amdgcn_s_sleep(1);
          if (++guard > (1<<22)) break;
        }
        int m = v;
        #pragma unroll
        for (int o = 8; o; o >>= 1) m = min(m, __shfl_xor(m, o));
        ackmin = __shfl(m, 0);
      }
    }

    short8 Bx[NKX];
    if constexpr (!HASX){
      // layer 0: x is a plain L1/L2-cached load, issued before the poll
      const float* px = x + ((size_t)bloc*NT + t)*DIN + quad*8;
      #pragma unroll
      for (int k = 0; k < NKX; ++k) Bx[k] = ld8f_frag(px + k*32);
    }

    // ---- one merged wait: h counters >= t (trivial at t=0), x >= t+1 ----
    poll2(tagOwn, t, tagPrev, t+1, lane);

    // ---- stage planes into LDS (double-buffered, one barrier/step) ----
    u64* ldsX = ldsb[(t&1)*2 + 0];
    u64* ldsH = ldsb[(t&1)*2 + 1];
    if constexpr (HASX)
      stage_plane(ringPrev + (size_t)slot*SLOT_U64 + (size_t)bg*16*64, ldsX, wv, lane);
    if (t > 0)
      stage_plane(ringOwn + (size_t)pslot*SLOT_U64 + (size_t)bg*16*64, ldsH, wv, lane);
    __syncthreads();

    // ack prev-layer slot consumed (stage loads complete: barrier passed)
    if (HASX && wrap && ((t & 7) == 7) && lane == 0) st_flag(ackPrevW, t+1);

    if constexpr (HASX){
      #pragma unroll
      for (int k = 0; k < NKX; ++k) Bx[k] = lds_frag(ldsX, l15, quad*8 + k*32);
    }
    short8 Bh[8];
    if (t == 0){
      const float* ph = h0 + ((size_t)l*NB + bloc)*NH + quad*8;
      #pragma unroll
      for (int k = 0; k < 8; ++k) Bh[k] = ld8f_frag(ph + k*32);
    } else {
      #pragma unroll
      for (int k = 0; k < 8; ++k) Bh[k] = lds_frag(ldsH, l15, quad*8 + k*32);
    }

    // ---- MFMAs: x-part then h-part ----
    f32x4 a0 = {0,0,0,0}, a1 = {0,0,0,0}, a2 = {0,0,0,0}, a3 = {0,0,0,0};
    #pragma unroll
    for (int k = 0; k < NKX; ++k){
      a0 = __builtin_amdgcn_mfma_f32_16x16x32_bf16(A[0][k], Bx[k], a0, 0, 0, 0);
      a1 = __builtin_amdgcn_mfma_f32_16x16x32_bf16(A[1][k], Bx[k], a1, 0, 0, 0);
      a2 = __builtin_amdgcn_mfma_f32_16x16x32_bf16(A[2][k], Bx[k], a2, 0, 0, 0);
      a3 = __builtin_amdgcn_mfma_f32_16x16x32_bf16(A[3][k], Bx[k], a3, 0, 0, 0);
    }
    #pragma unroll
    for (int k = 0; k < 8; ++k){
      a0 = __builtin_amdgcn_mfma_f32_16x16x32_bf16(A[0][NKX+k], Bh[k], a0, 0, 0, 0);
      a1 = __builtin_amdgcn_mfma_f32_16x16x32_bf16(A[1][NKX+k], Bh[k], a1, 0, 0, 0);
      a2 = __builtin_amdgcn_mfma_f32_16x16x32_bf16(A[2][NKX+k], Bh[k], a2, 0, 0, 0);
      a3 = __builtin_amdgcn_mfma_f32_16x16x32_bf16(A[3][NKX+k], Bh[k], a3, 0, 0, 0);
    }

    // ---- fused gate nonlinearities + state update ----
    float hv[4];
    #pragma unroll
    for (int r = 0; r < 4; ++r){
      float ig = sigmf(a0[r] + bsv[0][r]);
      float fg = sigmf(a1[r] + bsv[1][r]);
      float gv = tanhfast(a2[r] + bsv[2][r]);
      float og = sigmf(a3[r] + bsv[3][r]);
      float cn = fg*cc[r] + ig*gv;
      cc[r] = cn;
      hv[r] = og * tanhfast(cn);
    }

    // ---- publish: 8B store -> drain -> monotone counter ----
    ring_st(ringOwn + (size_t)slot*SLOT_U64 + (size_t)bloc*64 + s*4 + quad,
            f2bf4(hv[0], hv[1], hv[2], hv[3]));
    if (t == NT-1){
      f32x4 ov; ov[0]=hv[0]; ov[1]=hv[1]; ov[2]=hv[2]; ov[3]=hv[3];
      *(f32x4*)(out + ((size_t)l*NB + bloc)*NH + jcol) = ov;
    }
    asm volatile("s_waitcnt vmcnt(0)" ::: "memory");
    if (lane == 0) st_flag(tagOwn + s, t+1);
  }
}

__global__ __launch_bounds__(256, 1)
void lstm_pipe(const float* __restrict__ x,   const float* __restrict__ h0,
               const float* __restrict__ c0,  const float* __restrict__ wih0,
               const float* __restrict__ wih, const float* __restrict__ whh,
               const float* __restrict__ bih, const float* __restrict__ bhh,
               float* __restrict__ out, int* __restrict__ tags,
               int* __restrict__ acks, u64* __restrict__ ring, int Wv)
{
  // XCD clustering: bid = bg + 8*(l*4 + b). With bid%8 XCD round-robin, the
  // entire 6-layer pipeline of batch-group bg (24 blocks) lands on one XCD.
  __shared__ u64 ldsb[4][1056];   // [buf 2][plane x/h][16 rows x 66 u64 (528B)]
  const int bid  = blockIdx.x;
  const int bg   = bid & 7;
  const int j    = bid >> 3;
  const int l    = j >> 2;
  const int b    = j & 3;
  const int lane = threadIdx.x & 63;
  const int wv   = threadIdx.x >> 6;
  const int s    = b*4 + wv;          // this wave's slice (0..15)

  if (l == 0)
    lstm_run<4>(x, h0, c0, wih0, whh, bih, bhh,
                out, tags, acks, ring, ldsb, Wv, 0, bg, s, wv, lane);
  else
    lstm_run<8>(x, h0, c0,
                wih + (size_t)(l-1)*(4*NH*NH),
                whh + (size_t)l*(4*NH*NH),
                bih + (size_t)l*(4*NH),
                bhh + (size_t)l*(4*NH),
                out, tags, acks, ring, ldsb, Wv, l, bg, s, wv, lane);
}

extern "C" void kernel_launch(void* const* d_in, const int* in_sizes, int n_in,
                              void* d_out, int out_size, void* d_ws, size_t ws_size,
                              hipStream_t stream)
{
  (void)in_sizes; (void)n_in; (void)out_size;
  const float* x    = (const float*)d_in[0];
  const float* h0   = (const float*)d_in[1];
  const float* c0   = (const float*)d_in[2];
  const float* wih0 = (const float*)d_in[3];
  const float* wih  = (const float*)d_in[4];
  const float* whh  = (const float*)d_in[5];
  const float* bih  = (const float*)d_in[6];
  const float* bhh  = (const float*)d_in[7];

  // Full-depth ring preferred (no wrap machinery); shrink if ws is small.
  int Wv = NT;
  size_t ringB;
  for (;;){
    ringB = (size_t)NLAYER*Wv*SLOT_U64*8;
    if (8192 + ringB <= ws_size || Wv <= 32) break;
    Wv >>= 1;
  }

  int* tags = (int*)d_ws;                      // 48 groups x 16 counters
  int* acks = (int*)((char*)d_ws + 4096);      // 48 groups x 16 watermarks
  u64* ring = (u64*)((char*)d_ws + 8192);

  // Counters monotone from 0 => ring data is only trusted after this
  // launch's counters advance; ring itself needs no clearing.
  (void)hipMemsetAsync(d_ws, 0, 8192, stream);
  hipLaunchKernelGGL(lstm_pipe, dim3(NBLK), dim3(256), 0, stream,
                     x, h0, c0, wih0, wih, whh, bih, bhh,
                     (float*)d_out, tags, acks, ring, Wv);
}

// Round 3
// 2090.520 us; speedup vs baseline: 2.2107x; 1.0948x over previous
//
#include <hip/hip_runtime.h>

#define NLAYER 6
#define NB     128     // batch
#define NT     512     // seq len
#define DIN    128     // layer-0 input size
#define NH     256     // hidden
#define NBLK   192     // 6 layers x 8 batch-groups x 4 blocks
// Tagged ring: each h value is one 4B word = (bf16<<16)|step_tag.
// Slot = [128 batch rows][256 words] = 128KB = 16384 u64.
#define TSLOT_U64 (NB*NH/2)

typedef __attribute__((ext_vector_type(8))) short short8;
typedef __attribute__((ext_vector_type(4))) float f32x4;
typedef unsigned long long u64;

__device__ __forceinline__ unsigned f2bf2(float lo, float hi){
  unsigned a = __float_as_uint(lo), b = __float_as_uint(hi);
  a = (a + 0x7fffu + ((a>>16)&1u)) >> 16;   // RNE bf16
  b = (b + 0x7fffu + ((b>>16)&1u)) >> 16;
  return a | (b<<16);
}
__device__ __forceinline__ u64 f2bf4(float a, float b, float c, float d){
  return (u64)f2bf2(a,b) | ((u64)f2bf2(c,d) << 32);
}
__device__ __forceinline__ short8 pack16(u64 lo, u64 hi){
  union { u64 u[2]; short8 v; } w; w.u[0]=lo; w.u[1]=hi; return w.v;
}
// 8 consecutive fp32 -> one MFMA bf16 fragment (4 VGPRs)
__device__ __forceinline__ short8 ld8f_frag(const float* p){
  f32x4 a = *(const f32x4*)p;
  f32x4 b = *(const f32x4*)(p+4);
  return pack16(f2bf4(a[0],a[1],a[2],a[3]), f2bf4(b[0],b[1],b[2],b[3]));
}

__device__ __forceinline__ float sigmf(float v){ return 1.0f/(1.0f + __expf(-v)); }
__device__ __forceinline__ float tanhfast(float v){
  v = fminf(fmaxf(v, -15.0f), 15.0f);
  float e = __expf(2.0f*v);
  return (e - 1.0f)/(e + 1.0f);
}

// Relaxed agent-scope atomics (device-coherent). With self-validating tagged
// words the ONLY requirement is per-4B-word atomic visibility: no store
// ordering, no vmcnt drain, no separate tag arrays.
__device__ __forceinline__ int ld_flag(const int* p){
  return __hip_atomic_load(p, __ATOMIC_RELAXED, __HIP_MEMORY_SCOPE_AGENT);
}
__device__ __forceinline__ void st_flag(int* p, int v){
  __hip_atomic_store(p, v, __ATOMIC_RELAXED, __HIP_MEMORY_SCOPE_AGENT);
}
__device__ __forceinline__ u64 ring_ld(const u64* p){
  return __hip_atomic_load(p, __ATOMIC_RELAXED, __HIP_MEMORY_SCOPE_AGENT);
}
__device__ __forceinline__ void ring_st(u64* p, u64 v){
  __hip_atomic_store(p, v, __ATOMIC_RELAXED, __HIP_MEMORY_SCOPE_AGENT);
}

// one h value + step tag -> self-validating 4B word
__device__ __forceinline__ unsigned tagw(float f, unsigned tag){
  unsigned a = __float_as_uint(f);
  return ((a + 0x7fffu + ((a>>16)&1u)) & 0xffff0000u) | tag;   // RNE bf16 in hi16
}
// strip tags: two tagged u64 (4 words) -> one packed u64 (4 bf16)
__device__ __forceinline__ unsigned strip2(u64 q){
  return __builtin_amdgcn_perm((unsigned)(q>>32), (unsigned)q, 0x07060302u);
}

// MFMA B-fragment from a staged LDS plane (row pitch 132 u32 = 528B:
// +16B pad keeps ds_read_b128 at the free 2-way aliasing level).
__device__ __forceinline__ short8 lds_frag(const unsigned* __restrict__ buf, int row, int soff){
  return *(const short8*)((const short*)buf + row*264 + soff);
}

// Block = 4 slices x 16 batch rows. Wave wv owns slice s = b*4+wv. h/x are
// staged once per block into LDS via POLLING tagged loads (the stage IS the
// sync); A stationary in regs; publish is fire-and-forget tagged stores.
template<int NKX>
__device__ __forceinline__ void lstm_run(
    const float* __restrict__ x,  const float* __restrict__ h0,
    const float* __restrict__ c0, const float* __restrict__ wx,
    const float* __restrict__ wh, const float* __restrict__ bi,
    const float* __restrict__ bh, float* __restrict__ out,
    int* __restrict__ acks, u64* __restrict__ ring, unsigned (*ldsb)[2112],
    int Wv, int l, int bg, int s, int wv, int lane)
{
  constexpr int KIT  = NKX + 8;      // total k-iterations (12 or 16)
  constexpr int KX   = NKX*32;       // input width (128 or 256)
  constexpr bool HASX = (NKX == 8);  // x comes from the prev-layer ring
  const int l15  = lane & 15;
  const int quad = lane >> 4;
  const int bloc = bg*16 + l15;      // this lane's batch row
  const int jcol = s*16 + quad*4;    // this lane's first hidden col
  const int Wm   = Wv - 1;

  // ---- A fragments: stationary (4 gates x KIT kts x 4 VGPR) ----
  short8 A[4][KIT];
  #pragma unroll
  for (int q = 0; q < 4; ++q){
    const float* wrow_x = wx + (size_t)(q*NH + s*16 + l15)*KX;
    const float* wrow_h = wh + (size_t)(q*NH + s*16 + l15)*NH;
    #pragma unroll
    for (int kt = 0; kt < KIT; ++kt){
      int k0 = kt*32 + quad*8;
      A[q][kt] = (k0 < KX) ? ld8f_frag(wrow_x + k0)
                           : ld8f_frag(wrow_h + (k0 - KX));
    }
  }

  f32x4 bsv[4];
  #pragma unroll
  for (int q = 0; q < 4; ++q){
    f32x4 a = *(const f32x4*)(bi + q*NH + jcol);
    f32x4 b = *(const f32x4*)(bh + q*NH + jcol);
    bsv[q] = a + b;
  }
  float cc[4];
  {
    f32x4 cv = *(const f32x4*)(c0 + ((size_t)l*NB + bloc)*NH + jcol);
    cc[0]=cv[0]; cc[1]=cv[1]; cc[2]=cv[2]; cc[3]=cv[3];
  }

  const int* ackOwn = acks + (l*8 + bg)*16;                     // layer l+1 watermarks
  int* ackPrevW = HASX ? acks + ((l-1)*8 + bg)*16 + s : nullptr;
  const u64* ringPrev = HASX ? ring + (size_t)(l-1)*Wv*TSLOT_U64 : nullptr;
  u64*       ringOwn  = ring + (size_t)l*Wv*TSLOT_U64;
  const bool lastL = (l == NLAYER-1);
  const bool wrap  = (Wv < NT);
  int ackmin = 0;

  // per-lane stage geometry: chunk c covers plane row wv*4+c, 16B per lane
  const int sbase = wv*512 + lane*2;   // u64 index within a 2048-u64 plane

  for (int t = 0; t < NT; ++t){
    const int slot  = t & Wm;
    const int pslot = (t-1) & Wm;

    // WAR guard (wrap only): layer l+1 must have consumed slot t-Wv.
    // Consumers ack every 8 steps; cached watermark -> fabric poll ~1/8 steps.
    if (wrap && !lastL && t >= Wv){
      const int need = t - Wv + 1;
      if (ackmin < need){
        int v = 0, guard = 0;
        for (;;){
          v = (lane < 16) ? ld_flag(ackOwn + lane) : 0x7fffffff;
          if (__ballot(v >= need) == ~0ull) break;
          __builtin_amdgcn_s_sleep(1);
          if (++guard > (1<<22)) break;
        }
        int m = v;
        #pragma unroll
        for (int o = 8; o; o >>= 1) m = min(m, __shfl_xor(m, o));
        ackmin = __shfl(m, 0);
      }
    }

    short8 Bx[NKX];
    if constexpr (!HASX){
      // layer 0: x is a plain cached load, issued before the h poll
      const float* px = x + ((size_t)bloc*NT + t)*DIN + quad*8;
      #pragma unroll
      for (int k = 0; k < NKX; ++k) Bx[k] = ld8f_frag(px + k*32);
    }

    // ---- polling stage: tagged coalesced loads, retry until valid ----
    const u64* srcX = HASX ? ringPrev + (size_t)slot*TSLOT_U64 + bg*2048 : nullptr;
    const u64* srcH = (t > 0) ? ringOwn + (size_t)pslot*TSLOT_U64 + bg*2048 : nullptr;
    unsigned* ldsX = ldsb[(t&1)*2 + 0];
    unsigned* ldsH = ldsb[(t&1)*2 + 1];
    u64 qx[8], qh[8];
    {
      bool okx = !HASX, okh = (srcH == nullptr);
      const u64 tx2 = (u64)(unsigned)(t+1) * 0x0000000100000001ull;
      const u64 th2 = (u64)(unsigned)t     * 0x0000000100000001ull;
      int guard = 0;
      while (!(okx & okh)){
        if (!okx){
          #pragma unroll
          for (int c = 0; c < 4; ++c){
            qx[c*2]   = ring_ld(srcX + sbase + c*128);
            qx[c*2+1] = ring_ld(srcX + sbase + c*128 + 1);
          }
        }
        if (!okh){
          #pragma unroll
          for (int c = 0; c < 4; ++c){
            qh[c*2]   = ring_ld(srcH + sbase + c*128);
            qh[c*2+1] = ring_ld(srcH + sbase + c*128 + 1);
          }
        }
        if (!okx){
          u64 m = 0;
          #pragma unroll
          for (int i = 0; i < 8; ++i) m |= qx[i] ^ tx2;
          okx = (__ballot(((unsigned)(m | (m>>32)) & 0xffffu) == 0u) == ~0ull);
        }
        if (!okh){
          u64 m = 0;
          #pragma unroll
          for (int i = 0; i < 8; ++i) m |= qh[i] ^ th2;
          okh = (__ballot(((unsigned)(m | (m>>32)) & 0xffffu) == 0u) == ~0ull);
        }
        if (okx & okh) break;
        __builtin_amdgcn_s_sleep(1);
        if (++guard > (1<<20)) break;   // failsafe only
      }
    }
    // strip tags -> packed bf16 planes in LDS (lane-contiguous: conflict-free)
    if constexpr (HASX){
      #pragma unroll
      for (int c = 0; c < 4; ++c)
        *(u64*)(ldsX + (wv*4+c)*132 + lane*2) =
            (u64)strip2(qx[c*2]) | ((u64)strip2(qx[c*2+1]) << 32);
    }
    if (srcH){
      #pragma unroll
      for (int c = 0; c < 4; ++c)
        *(u64*)(ldsH + (wv*4+c)*132 + lane*2) =
            (u64)strip2(qh[c*2]) | ((u64)strip2(qh[c*2+1]) << 32);
    }
    __syncthreads();

    // ack prev-layer consumption every 8 steps (values were branched on ->
    // loads complete; relaxed flag is sufficient for the WAR watermark)
    if (HASX && wrap && ((t & 7) == 7) && lane == 0) st_flag(ackPrevW, t+1);

    if constexpr (HASX){
      #pragma unroll
      for (int k = 0; k < NKX; ++k) Bx[k] = lds_frag(ldsX, l15, quad*8 + k*32);
    }
    short8 Bh[8];
    if (t == 0){
      const float* ph = h0 + ((size_t)l*NB + bloc)*NH + quad*8;
      #pragma unroll
      for (int k = 0; k < 8; ++k) Bh[k] = ld8f_frag(ph + k*32);
    } else {
      #pragma unroll
      for (int k = 0; k < 8; ++k) Bh[k] = lds_frag(ldsH, l15, quad*8 + k*32);
    }

    // ---- MFMAs: x-part then h-part ----
    f32x4 a0 = {0,0,0,0}, a1 = {0,0,0,0}, a2 = {0,0,0,0}, a3 = {0,0,0,0};
    #pragma unroll
    for (int k = 0; k < NKX; ++k){
      a0 = __builtin_amdgcn_mfma_f32_16x16x32_bf16(A[0][k], Bx[k], a0, 0, 0, 0);
      a1 = __builtin_amdgcn_mfma_f32_16x16x32_bf16(A[1][k], Bx[k], a1, 0, 0, 0);
      a2 = __builtin_amdgcn_mfma_f32_16x16x32_bf16(A[2][k], Bx[k], a2, 0, 0, 0);
      a3 = __builtin_amdgcn_mfma_f32_16x16x32_bf16(A[3][k], Bx[k], a3, 0, 0, 0);
    }
    #pragma unroll
    for (int k = 0; k < 8; ++k){
      a0 = __builtin_amdgcn_mfma_f32_16x16x32_bf16(A[0][NKX+k], Bh[k], a0, 0, 0, 0);
      a1 = __builtin_amdgcn_mfma_f32_16x16x32_bf16(A[1][NKX+k], Bh[k], a1, 0, 0, 0);
      a2 = __builtin_amdgcn_mfma_f32_16x16x32_bf16(A[2][NKX+k], Bh[k], a2, 0, 0, 0);
      a3 = __builtin_amdgcn_mfma_f32_16x16x32_bf16(A[3][NKX+k], Bh[k], a3, 0, 0, 0);
    }

    // ---- fused gate nonlinearities + state update ----
    float hv[4];
    #pragma unroll
    for (int r = 0; r < 4; ++r){
      float ig = sigmf(a0[r] + bsv[0][r]);
      float fg = sigmf(a1[r] + bsv[1][r]);
      float gv = tanhfast(a2[r] + bsv[2][r]);
      float og = sigmf(a3[r] + bsv[3][r]);
      float cn = fg*cc[r] + ig*gv;
      cc[r] = cn;
      hv[r] = og * tanhfast(cn);
    }

    // ---- publish: two self-tagged 8B stores. Fire-and-forget: no drain,
    // no tag store. Per-4B-word atomicity carries the protocol.
    u64* hp = ringOwn + (size_t)slot*TSLOT_U64 + (size_t)bloc*128 + s*8 + quad*2;
    const unsigned otag = (unsigned)(t+1);
    ring_st(hp,     (u64)tagw(hv[0], otag) | ((u64)tagw(hv[1], otag) << 32));
    ring_st(hp + 1, (u64)tagw(hv[2], otag) | ((u64)tagw(hv[3], otag) << 32));
    if (t == NT-1){
      f32x4 ov; ov[0]=hv[0]; ov[1]=hv[1]; ov[2]=hv[2]; ov[3]=hv[3];
      *(f32x4*)(out + ((size_t)l*NB + bloc)*NH + jcol) = ov;
    }
  }
}

__global__ __launch_bounds__(256, 1)
void lstm_pipe(const float* __restrict__ x,   const float* __restrict__ h0,
               const float* __restrict__ c0,  const float* __restrict__ wih0,
               const float* __restrict__ wih, const float* __restrict__ whh,
               const float* __restrict__ bih, const float* __restrict__ bhh,
               float* __restrict__ out, int* __restrict__ acks,
               u64* __restrict__ ring, int Wv)
{
  // XCD clustering: bid = bg + 8*(l*4 + b). With bid%8 XCD round-robin, the
  // entire 6-layer pipeline of batch-group bg (24 blocks) lands on one XCD.
  __shared__ unsigned ldsb[4][2112];   // [buf 2][plane x/h][16 rows x 132 u32]
  const int bid  = blockIdx.x;
  const int bg   = bid & 7;
  const int j    = bid >> 3;
  const int l    = j >> 2;
  const int b    = j & 3;
  const int lane = threadIdx.x & 63;
  const int wv   = threadIdx.x >> 6;
  const int s    = b*4 + wv;          // this wave's slice (0..15)

  if (l == 0)
    lstm_run<4>(x, h0, c0, wih0, whh, bih, bhh,
                out, acks, ring, ldsb, Wv, 0, bg, s, wv, lane);
  else
    lstm_run<8>(x, h0, c0,
                wih + (size_t)(l-1)*(4*NH*NH),
                whh + (size_t)l*(4*NH*NH),
                bih + (size_t)l*(4*NH),
                bhh + (size_t)l*(4*NH),
                out, acks, ring, ldsb, Wv, l, bg, s, wv, lane);
}

extern "C" void kernel_launch(void* const* d_in, const int* in_sizes, int n_in,
                              void* d_out, int out_size, void* d_ws, size_t ws_size,
                              hipStream_t stream)
{
  (void)in_sizes; (void)n_in; (void)out_size;
  const float* x    = (const float*)d_in[0];
  const float* h0   = (const float*)d_in[1];
  const float* c0   = (const float*)d_in[2];
  const float* wih0 = (const float*)d_in[3];
  const float* wih  = (const float*)d_in[4];
  const float* whh  = (const float*)d_in[5];
  const float* bih  = (const float*)d_in[6];
  const float* bhh  = (const float*)d_in[7];

  // Ring depth 32 (25 MB tagged). Own-h cohort is lockstep (skew <= 1) so
  // any depth >= 2 is safe there; cross-layer wrap uses amortized acks.
  int Wv = 32;
  size_t ringB;
  for (;;){
    ringB = (size_t)NLAYER*Wv*TSLOT_U64*8;
    if (8192 + ringB <= ws_size || Wv <= 8) break;
    Wv >>= 1;
  }

  int* acks = (int*)d_ws;                    // 768 ints, padded to 8KB
  u64* ring = (u64*)((char*)d_ws + 8192);

  // Ring MUST be cleared every launch: graph replay would otherwise find the
  // previous run's tags (identical t+1 pattern) and accept stale data.
  // Tag 0 never validates (expected tags are >= 1).
  (void)hipMemsetAsync(d_ws, 0, 8192 + ringB, stream);
  hipLaunchKernelGGL(lstm_pipe, dim3(NBLK), dim3(256), 0, stream,
                     x, h0, c0, wih0, wih, whh, bih, bhh,
                     (float*)d_out, acks, ring, Wv);
}